// Round 7
// baseline (2978.703 us; speedup 1.0000x reference)
//
#include <hip/hip_runtime.h>
#include <stdint.h>

// ---------------------------------------------------------------------------
// 2-layer LSTM, B=64, T=512, E=512, H=1024, then [64,1024]@V.T+bV -> [64,10].
//
// Round 11: R10 (proven, 2955us, bank-conflict 0) + 2-deep pipelined flag
// polls. R10 showed conflicts were hidden under the latency chain; the
// reducible term is poll SAMPLING (each iteration was load+vmcnt(0) = 1 IC RT
// spacing). New pollp(): 2 loads in flight, counted vmcnt(1), register-tied
// claims ("+v") + sched_barrier(0) per guide rule #18 -> sampling ~RT/2.
// Stale samples are safe (monotonic flags, >= check); claims pin pending regs.
// Rendezvous (4/run) keeps proven poll128. All else byte-identical to R10.
// ---------------------------------------------------------------------------

typedef __attribute__((ext_vector_type(8))) short bf16x8;
typedef __attribute__((ext_vector_type(4))) float f32x4;
typedef unsigned short ush;
typedef unsigned int u32;

__device__ __forceinline__ ush f2bf(float x) {
    unsigned u = __float_as_uint(x);
    u = (u + 0x7FFFu + ((u >> 16) & 1u)) >> 16;   // RNE
    return (ush)u;
}

__device__ __forceinline__ f32x4 mfma16(bf16x8 a, bf16x8 b, f32x4 c) {
    return __builtin_amdgcn_mfma_f32_16x16x32_bf16(a, b, c, 0, 0, 0);
}

__device__ __forceinline__ float fsigm(float x) {
    x = fminf(fmaxf(x, -60.f), 60.f);
    return __builtin_amdgcn_rcpf(1.f + __expf(-x));
}
__device__ __forceinline__ float ftanh(float x) {
    x = fminf(fmaxf(x, -15.f), 15.f);
    float e = __expf(-2.f * x);
    return (1.f - e) * __builtin_amdgcn_rcpf(1.f + e);
}

// ---- proven access primitives --------------------------------------------
__device__ __forceinline__ u32 aload(const u32* p) {
    return __hip_atomic_load(p, __ATOMIC_RELAXED, __HIP_MEMORY_SCOPE_AGENT);
}
__device__ __forceinline__ void astore(u32* p, u32 v) {
    __hip_atomic_store(p, v, __ATOMIC_RELAXED, __HIP_MEMORY_SCOPE_AGENT);
}
// agent-scope 16B load (IC-direct, fallback path)
__device__ __forceinline__ bf16x8 ldh(const ush* p) {
    union { unsigned long long q[2]; bf16x8 v; } u;
    unsigned long long* a = (unsigned long long*)p;
    u.q[0] = __hip_atomic_load(a + 0, __ATOMIC_RELAXED, __HIP_MEMORY_SCOPE_AGENT);
    u.q[1] = __hip_atomic_load(a + 1, __ATOMIC_RELAXED, __HIP_MEMORY_SCOPE_AGENT);
    return u.v;
}

__device__ __forceinline__ void poll64(const u32* base, int lane, unsigned target) {
    const u32* p = base + lane;
    for (;;) {
        unsigned a = aload(p);
        if (__all((int)(a >= target))) break;
        __builtin_amdgcn_s_sleep(2);
    }
}
__device__ __forceinline__ void poll128(const u32* base, int lane, unsigned target) {
    const u32* p0 = base + lane;
    const u32* p1 = base + 64 + lane;
    for (;;) {
        unsigned a = aload(p0);
        unsigned b = aload(p1);
        if (__all((int)((a >= target) && (b >= target)))) break;
        __builtin_amdgcn_s_sleep(2);
    }
}

// 2-deep pipelined poll: 2 IC loads in flight, sampling interval ~RT/2.
// Safe: flags monotonic, check is >=, stale sample only extends the wait.
// "+v" claims pin the pending-load registers; sched_barrier(0) pins order.
__device__ __forceinline__ void pollp(const u32* p, unsigned target) {
    u32 a, b;
    asm volatile("global_load_dword %0, %1, off sc0 sc1" : "=v"(a) : "v"(p) : "memory");
    asm volatile("global_load_dword %0, %1, off sc0 sc1" : "=v"(b) : "v"(p) : "memory");
    for (;;) {
        asm volatile("s_waitcnt vmcnt(1)" : "+v"(a) :: "memory");   // oldest (a) done
        __builtin_amdgcn_sched_barrier(0);
        if (__all((int)(a >= target))) break;
        asm volatile("global_load_dword %0, %1, off sc0 sc1" : "=v"(a) : "v"(p) : "memory");
        asm volatile("s_waitcnt vmcnt(1)" : "+v"(b) :: "memory");   // oldest (b) done
        __builtin_amdgcn_sched_barrier(0);
        if (__all((int)(b >= target))) break;
        asm volatile("global_load_dword %0, %1, off sc0 sc1" : "=v"(b) : "v"(p) : "memory");
        __builtin_amdgcn_s_sleep(1);
    }
    asm volatile("s_waitcnt vmcnt(0)" ::: "memory");                // drain leftover
    __builtin_amdgcn_sched_barrier(0);
}

// ---------------- embedding gather + bf16 convert --------------------------
__global__ __launch_bounds__(256) void embed_kernel(
    const int* __restrict__ x, const float* __restrict__ emb,
    ush* __restrict__ xs)
{
    int e = blockIdx.x * 256 + threadIdx.x;
    int t  = e >> 12;
    int rr = e & 4095;
    int b  = rr >> 6;
    int k8 = (rr & 63) << 3;
    int tok = x[b * 512 + t];
    const float* src = emb + (size_t)tok * 512 + k8;
    ush* dst = xs + ((size_t)(t * 64 + b)) * 512 + k8;
#pragma unroll
    for (int i = 0; i < 8; ++i) dst[i] = f2bf(src[i]);
}

__global__ __launch_bounds__(256) void init_kernel(u32* __restrict__ p, int n)
{
    int i = blockIdx.x * 256 + threadIdx.x;
    if (i < n) p[i] = 0u;
}

// ---- layout ---------------------------------------------------------------
#define OFF_H1F 67108864ULL
#define OFF_BAR 67371008ULL
// fallback (R3) defines
#define LDS_GWS_OFF 131072
#define RELIDX      2048
#define RING_MASK   127
#define SLOT_USH    65536
#define NBANK       16
// gws: 16 tiles x 264 floats (pad 8) after 131072B Afrag
#define GT_STRIDE   264
#define LDS_DF_TOTAL (131072 + 16 * GT_STRIDE * 4)   // 147968
#define LDS_FB_TOTAL 148480

// ---------------- persistent LSTM kernel: DATAFLOW -------------------------
__global__ __launch_bounds__(512) void lstm_kernel_df(
    const ush* __restrict__ xs,
    ush* __restrict__ h0ring,  // [128][64][1024] bf16
    ush* __restrict__ h1ring,  // [128][64][1024] bf16
    float* __restrict__ h1f,   // [64][1024] fp32
    u32* __restrict__ bar,
    const float* __restrict__ W0, const float* __restrict__ b0,
    const float* __restrict__ W1, const float* __restrict__ b1)
{
    extern __shared__ char smem[];
    bf16x8* Afrag = (bf16x8*)smem;                 // [kb<32][4 gt][64 lanes]
    float*  gws   = (float*)(smem + LDS_GWS_OFF);  // 16 tiles * 264 floats

    const int wg  = blockIdx.x;
    const int tid = threadIdx.x;
    const bool isL1 = (wg >= 128);
    const int rr  = wg & 127;
    const int g   = rr >> 6;         // batch group 0/1
    const int w   = rr & 63;         // column block (cols 16w..16w+16)
    const int w16 = w * 16;
    const float* W = isL1 ? W1 : W0;
    const int wstride = isL1 ? 2048 : 1536;
    const float* bias = isL1 ? b1 : b0;
    const u32* bk = bar + (wg & (NBANK - 1)) * 256;

    // ---- LDS A-fragments: kb 0..31, 4 gate-tiles, 64 lanes (131072 B) ----
    for (int f = tid; f < 8192; f += 512) {
        int laneE = f & 63;
        int gt    = (f >> 6) & 3;
        int kb    = f >> 8;
        int m16   = laneE & 15;
        int q     = laneE >> 4;
        int c     = m16 >> 2;
        int s     = m16 & 3;
        int grow  = c * 1024 + w16 + gt * 4 + s;
        const float* src = W + (size_t)grow * wstride + kb * 32 + q * 8;
        bf16x8 v;
#pragma unroll
        for (int i = 0; i < 8; ++i) v[i] = (short)f2bf(src[i]);
        Afrag[f] = v;
    }

    const int lane = tid & 63;
    const int wid  = tid >> 6;         // 0..7
    const int bt   = wid & 1;          // batch sub-tile
    const int ksh  = wid >> 1;         // K-quarter 0..3
    const int n16  = lane & 15;
    const int q4   = lane >> 4;
    const int row  = g * 32 + bt * 16 + n16;
    const int nkreg = isL1 ? 8 : 4;

    // ---- register A-fragments: kb = 32 + ksh + 4*jr ----
    bf16x8 rfb[8][4];
    {
        int m16 = lane & 15;
        int q   = lane >> 4;
        int c   = m16 >> 2;
        int s   = m16 & 3;
#pragma unroll
        for (int jr = 0; jr < 8; ++jr) {
            if (jr < nkreg) {
                int kb = 32 + ksh + 4 * jr;
#pragma unroll
                for (int gt = 0; gt < 4; ++gt) {
                    int grow = c * 1024 + w16 + gt * 4 + s;
                    const float* src = W + (size_t)grow * wstride + kb * 32 + q * 8;
                    bf16x8 v;
#pragma unroll
                    for (int i = 0; i < 8; ++i) v[i] = (short)f2bf(src[i]);
                    rfb[jr][gt] = v;
                }
            }
        }
    }

    // ---- epilogue mapping: 1 cell/thread ----
    const int eb   = tid >> 4;        // local batch 0..31
    const int ecol = tid & 15;        // local column 0..15
    const int ebt  = tid >> 8;        // batch sub-tile
    const int en   = eb & 15;
    const int egt  = ecol >> 2;
    const int es   = ecol & 3;
    const int erow = g * 32 + eb;
    float bi[4];
#pragma unroll
    for (int c = 0; c < 4; ++c) bi[c] = bias[c * 1024 + w16 + ecol];
    float cst = 0.f;
    const float* rb0 = gws + (size_t)(ebt * 8 + egt) * GT_STRIDE + en * 4 + es;  // kp=0
    const float* rb1 = rb0 + 4 * GT_STRIDE;                                      // kp=1
    float* wb = gws + (size_t)(bt * 8 + (ksh & 1) * 4) * GT_STRIDE + lane * 4;

    __syncthreads();

    f32x4 acc[4];
#pragma unroll
    for (int i = 0; i < 4; ++i) acc[i] = (f32x4){0.f, 0.f, 0.f, 0.f};

    // pre-loop: L0's xs-part for t=0
    if (!isL1) {
        const ush* xsp = xs + ((size_t)row) * 512 + q4 * 8;
#pragma unroll
        for (int j = 0; j < 4; ++j) {
            int kb = ksh + 4 * j;
            bf16x8 bf = *(const bf16x8*)(xsp + kb * 32);
#pragma unroll
            for (int gt = 0; gt < 4; ++gt)
                acc[gt] = mfma16(Afrag[(kb * 4 + gt) * 64 + lane], bf, acc[gt]);
        }
    }

    for (int tick = 0; tick < 513; ++tick) {
        // ---- dependency wait (banked flags; 2-deep pipelined sampling) ----
        if (tick > 0) {
            unsigned target = (unsigned)tick;
            if ((tick & RING_MASK) == 0) {
                if (wid == 0)      poll128(bk,       lane, target);
                else if (wid == 4) poll128(bk + 128, lane, target);
                __syncthreads();
                if (wid == 0)
                    __builtin_amdgcn_fence(__ATOMIC_ACQUIRE, "agent");
                __syncthreads();
            } else {
                if (wid == 0)              pollp(bk + g * 64 + lane, target);
                else if (isL1 && wid == 4) pollp(bk + 128 + g * 64 + lane, target);
                __syncthreads();
            }
        }

        int t = isL1 ? (tick - 1) : tick;
        if (t >= 0 && t < 512) {
            if (!isL1) {
                // h0(t-1): ring slot (t-1)&127
                if (t > 0) {
                    const ush* hp =
                        h0ring + (size_t)((t - 1) & RING_MASK) * SLOT_USH
                               + (size_t)row * 1024 + q4 * 8;
#pragma unroll
                    for (int j = 4; j < 8; ++j) {          // kb 16..31 (LDS)
                        int kb = ksh + 4 * j;
                        bf16x8 bf = *(const bf16x8*)(hp + (kb - 16) * 32);
#pragma unroll
                        for (int gt = 0; gt < 4; ++gt)
                            acc[gt] = mfma16(Afrag[(kb * 4 + gt) * 64 + lane], bf, acc[gt]);
                    }
#pragma unroll
                    for (int j = 0; j < 4; ++j) {          // kb 32..47 (regs)
                        int kb = 32 + ksh + 4 * j;
                        bf16x8 bf = *(const bf16x8*)(hp + (kb - 16) * 32);
#pragma unroll
                        for (int gt = 0; gt < 4; ++gt)
                            acc[gt] = mfma16(rfb[j][gt], bf, acc[gt]);
                    }
                }
            } else {
                // h0(t): ring slot t&127 (LDS frags, kb 0..31)
                const ush* hp0 =
                    h0ring + (size_t)(t & RING_MASK) * SLOT_USH
                           + (size_t)row * 1024 + q4 * 8;
#pragma unroll
                for (int j = 0; j < 8; ++j) {
                    int kb = ksh + 4 * j;
                    bf16x8 bf = *(const bf16x8*)(hp0 + kb * 32);
#pragma unroll
                    for (int gt = 0; gt < 4; ++gt)
                        acc[gt] = mfma16(Afrag[(kb * 4 + gt) * 64 + lane], bf, acc[gt]);
                }
                // h1(t-1): ring slot (t-1)&127 (reg frags, kb 32..63)
                if (t > 0) {
                    const ush* hp1 =
                        h1ring + (size_t)((t - 1) & RING_MASK) * SLOT_USH
                               + (size_t)row * 1024 + q4 * 8;
#pragma unroll
                    for (int j = 0; j < 8; ++j) {
                        int kb = ksh + 4 * j;
                        bf16x8 bf = *(const bf16x8*)(hp1 + kb * 32);
#pragma unroll
                        for (int gt = 0; gt < 4; ++gt)
                            acc[gt] = mfma16(rfb[j][gt], bf, acc[gt]);
                    }
                }
            }

            // ---- K reduce: contiguous b128 per wave (conflict-free) ----
            if (ksh < 2) {
#pragma unroll
                for (int gt = 0; gt < 4; ++gt)
                    *(f32x4*)(wb + gt * GT_STRIDE) = acc[gt];
            }
            __syncthreads();   // (A1)
            if (ksh >= 2) {
#pragma unroll
                for (int gt = 0; gt < 4; ++gt) {
                    f32x4 v = *(const f32x4*)(wb + gt * GT_STRIDE);
                    v += acc[gt];
                    *(f32x4*)(wb + gt * GT_STRIDE) = v;
                }
            }
            __syncthreads();   // (A2)

            // ---- epilogue: one cell per thread (<=2-way banks) ----
            float xi = rb0[0]   + rb1[0]   + bi[0];
            float xf = rb0[64]  + rb1[64]  + bi[1];
            float xg = rb0[128] + rb1[128] + bi[2];
            float xo = rb0[192] + rb1[192] + bi[3];
            float si = fsigm(xi);
            float sf = fsigm(xf);
            float tg = ftanh(xg);
            float so = fsigm(xo);
            float cn = sf * cst + si * tg;
            cst = cn;
            float h  = so * ftanh(cn);
            unsigned hb  = (unsigned)f2bf(h);
            unsigned hup = (unsigned)__shfl_down((int)hb, 1);
            if (!(tid & 1)) {
                unsigned hv = hb | (hup << 16);
                ush* hw = (isL1 ? h1ring : h0ring) + (size_t)(t & RING_MASK) * SLOT_USH;
                u32* hp32 = (u32*)(hw + (size_t)erow * 1024 + w16 + ecol);
                astore(hp32, hv);
            }
            if (isL1 && t == 511)
                h1f[(size_t)erow * 1024 + w16 + ecol] = h;
            __syncthreads();   // (B) drain before flag
        }

        // ---- arrive: publish tick to all 16 banks ----
        if (tick < 512) {
            if (tid < NBANK) {
                astore(bar + tid * 256 + (isL1 ? 128 : 0) + g * 64 + w,
                       (unsigned)(tick + 1));
            }
#pragma unroll
            for (int i = 0; i < 4; ++i) acc[i] = (f32x4){0.f, 0.f, 0.f, 0.f};
            int tn = tick + 1;
            if (!isL1 && tn < 512) {    // xs-part overlaps flag propagation
                const ush* xsp = xs + ((size_t)(tn * 64 + row)) * 512 + q4 * 8;
#pragma unroll
                for (int j = 0; j < 4; ++j) {
                    int kb = ksh + 4 * j;
                    bf16x8 bf = *(const bf16x8*)(xsp + kb * 32);
#pragma unroll
                    for (int gt = 0; gt < 4; ++gt)
                        acc[gt] = mfma16(Afrag[(kb * 4 + gt) * 64 + lane], bf, acc[gt]);
                }
            }
        }
    }
}

// ---------------- persistent LSTM kernel: round-3 FALLBACK (small ws) ------
__global__ __launch_bounds__(512) void lstm_kernel_fb(
    const ush* __restrict__ xs,
    ush* __restrict__ h0buf,
    ush* __restrict__ h1buf,
    float* __restrict__ h1f,
    u32* __restrict__ bar,
    const float* __restrict__ W0, const float* __restrict__ b0,
    const float* __restrict__ W1, const float* __restrict__ b1)
{
    extern __shared__ char smem[];
    bf16x8* Afrag = (bf16x8*)smem;
    float*  gws   = (float*)(smem + LDS_GWS_OFF);

    const int wg  = blockIdx.x;
    const int tid = threadIdx.x;
    const bool isL1 = (wg >= 128);
    const int w   = isL1 ? wg - 128 : wg;
    const int w8  = w * 8;
    const int nk  = isL1 ? 64 : 48;
    const float* W = isL1 ? W1 : W0;
    const int wstride = isL1 ? 2048 : 1536;
    const float* bias = isL1 ? b1 : b0;

    for (int f = tid; f < nk * 128; f += 512) {
        int kblk = f >> 7;
        int rr   = f & 127;
        int mt   = rr >> 6;
        int lane = rr & 63;
        int m16  = lane & 15;
        int q    = lane >> 4;
        int c    = m16 >> 2;
        int ul   = mt * 4 + (m16 & 3);
        int grow = c * 1024 + w8 + ul;
        const float* src = W + (size_t)grow * wstride + kblk * 32 + q * 8;
        bf16x8 v;
#pragma unroll
        for (int i = 0; i < 8; ++i) v[i] = (short)f2bf(src[i]);
        Afrag[f] = v;
    }

    const int lane = tid & 63;
    const int wid  = tid >> 6;
    const int wv   = wid & 3;
    const int kh   = tid >> 8;
    const int n16  = lane & 15;
    const int q4   = lane >> 4;
    const int brow = wv * 16 + n16;

    float bi[2][4];
#pragma unroll
    for (int cell = 0; cell < 2; ++cell) {
        int j = w8 + q4 * 2 + cell;
#pragma unroll
        for (int c = 0; c < 4; ++c) bi[cell][c] = bias[c * 1024 + j];
    }
    float cst0 = 0.f, cst1 = 0.f;

    __syncthreads();

    f32x4 acc0 = (f32x4){0.f, 0.f, 0.f, 0.f};
    f32x4 acc1 = (f32x4){0.f, 0.f, 0.f, 0.f};

    if (!isL1) {
        const ush* xsp = xs + ((size_t)brow) * 512 + q4 * 8;
        int k0 = kh ? 8 : 0;
#pragma unroll
        for (int kb2 = 0; kb2 < 8; ++kb2) {
            int kb = k0 + kb2;
            bf16x8 bf = *(const bf16x8*)(xsp + kb * 32);
            acc0 = mfma16(Afrag[(kb * 2 + 0) * 64 + lane], bf, acc0);
            acc1 = mfma16(Afrag[(kb * 2 + 1) * 64 + lane], bf, acc1);
        }
    }

    for (int tick = 0; tick < 513; ++tick) {
        if (tick > 0) {
            unsigned target = (unsigned)tick;
            if (wg == 0) {
                if (tid < 256) {
                    while (aload(&bar[tid * 8]) < target)
                        __builtin_amdgcn_s_sleep(1);
                }
                __syncthreads();
                if (tid < 8)
                    astore(&bar[RELIDX + tid * 32], target);
            } else {
                if (tid == 0) {
                    while (aload(&bar[RELIDX + (wg & 7) * 32]) < target)
                        __builtin_amdgcn_s_sleep(1);
                }
                __syncthreads();
            }
            asm volatile("" ::: "memory");
        }

        int t = isL1 ? (tick - 1) : tick;
        if (t >= 0 && t < 512) {
            const int p = t & 1;

            if (!isL1) {
                const ush* hp = h0buf + (size_t)(p ^ 1) * 65536 + (size_t)brow * 1024 + q4 * 8;
                int k0 = kh ? 32 : 16;
#pragma unroll 8
                for (int kb2 = 0; kb2 < 16; ++kb2) {
                    int kb = k0 + kb2;
                    bf16x8 bf = ldh(hp + (kb - 16) * 32);
                    acc0 = mfma16(Afrag[(kb * 2 + 0) * 64 + lane], bf, acc0);
                    acc1 = mfma16(Afrag[(kb * 2 + 1) * 64 + lane], bf, acc1);
                }
            } else if (kh == 0) {
                const ush* hp0 = h0buf + (size_t)p * 65536 + (size_t)brow * 1024 + q4 * 8;
#pragma unroll 8
                for (int kb = 0; kb < 32; ++kb) {
                    bf16x8 bf = ldh(hp0 + kb * 32);
                    acc0 = mfma16(Afrag[(kb * 2 + 0) * 64 + lane], bf, acc0);
                    acc1 = mfma16(Afrag[(kb * 2 + 1) * 64 + lane], bf, acc1);
                }
            } else {
                const ush* hp1 = h1buf + (size_t)(p ^ 1) * 65536 + (size_t)brow * 1024 + q4 * 8;
#pragma unroll 8
                for (int kb = 32; kb < 64; ++kb) {
                    bf16x8 bf = ldh(hp1 + (kb - 32) * 32);
                    acc0 = mfma16(Afrag[(kb * 2 + 0) * 64 + lane], bf, acc0);
                    acc1 = mfma16(Afrag[(kb * 2 + 1) * 64 + lane], bf, acc1);
                }
            }

            float* gq = gws + wid * 512;
#pragma unroll
            for (int rr = 0; rr < 4; ++rr) {
                gq[      q4 * 64 + rr * 16 + n16] = acc0[rr];
                gq[256 + q4 * 64 + rr * 16 + n16] = acc1[rr];
            }
            __syncthreads();

            if (kh == 0) {
                ush* hw = (isL1 ? h1buf : h0buf) + (size_t)p * 65536;
                ush hbits[2];
                float hflt[2];
#pragma unroll
                for (int cell = 0; cell < 2; ++cell) {
                    int ul = q4 * 2 + cell;
                    int mt = ul >> 2;
                    int rr = ul & 3;
                    const float* g0 = gws + wv * 512 + mt * 256;
                    const float* g1 = gws + (wv + 4) * 512 + mt * 256;
                    float xi = g0[0 * 64 + rr * 16 + n16] + g1[0 * 64 + rr * 16 + n16] + bi[cell][0];
                    float xf = g0[1 * 64 + rr * 16 + n16] + g1[1 * 64 + rr * 16 + n16] + bi[cell][1];
                    float xg = g0[2 * 64 + rr * 16 + n16] + g1[2 * 64 + rr * 16 + n16] + bi[cell][2];
                    float xo = g0[3 * 64 + rr * 16 + n16] + g1[3 * 64 + rr * 16 + n16] + bi[cell][3];
                    float si = fsigm(xi);
                    float sf = fsigm(xf);
                    float tg = ftanh(xg);
                    float so = fsigm(xo);
                    float cprev = cell ? cst1 : cst0;
                    float cn = sf * cprev + si * tg;
                    if (cell) cst1 = cn; else cst0 = cn;
                    float h = so * ftanh(cn);
                    hflt[cell]  = h;
                    hbits[cell] = f2bf(h);
                }
                u32 hv = (u32)hbits[0] | ((u32)hbits[1] << 16);
                u32* hp32 = (u32*)(hw + (size_t)brow * 1024 + w8 + q4 * 2);
                astore(hp32, hv);
                if (isL1 && t == 511) {
                    h1f[(size_t)brow * 1024 + w8 + q4 * 2 + 0] = hflt[0];
                    h1f[(size_t)brow * 1024 + w8 + q4 * 2 + 1] = hflt[1];
                }
            }
            __syncthreads();
        }

        if (tick < 512) {
            if (tid == 0) {
                asm volatile("s_waitcnt vmcnt(0)" ::: "memory");
                astore(&bar[wg * 8], (unsigned)(tick + 1));
            }
            acc0 = (f32x4){0.f, 0.f, 0.f, 0.f};
            acc1 = (f32x4){0.f, 0.f, 0.f, 0.f};
            int tn = tick + 1;
            if (!isL1 && tn < 512) {
                const ush* xsp = xs + ((size_t)(tn * 64 + brow)) * 512 + q4 * 8;
                int k0 = kh ? 8 : 0;
#pragma unroll
                for (int kb2 = 0; kb2 < 8; ++kb2) {
                    int kb = k0 + kb2;
                    bf16x8 bf = *(const bf16x8*)(xsp + kb * 32);
                    acc0 = mfma16(Afrag[(kb * 2 + 0) * 64 + lane], bf, acc0);
                    acc1 = mfma16(Afrag[(kb * 2 + 1) * 64 + lane], bf, acc1);
                }
            }
        }
    }
}

// ---------------- classifier: out = h1f @ V.T + bV -------------------------
__global__ __launch_bounds__(64) void cls_kernel(
    const float* __restrict__ h1f, const float* __restrict__ V,
    const float* __restrict__ bV, float* __restrict__ out)
{
    int b = blockIdx.x;
    int lane = threadIdx.x;
    float p[10];
#pragma unroll
    for (int c = 0; c < 10; ++c) p[c] = 0.f;
    for (int k = lane; k < 1024; k += 64) {
        float h = h1f[(size_t)b * 1024 + k];
#pragma unroll
        for (int c = 0; c < 10; ++c) p[c] += h * V[(size_t)c * 1024 + k];
    }
#pragma unroll
    for (int c = 0; c < 10; ++c) {
        float v = p[c];
#pragma unroll
        for (int off = 32; off > 0; off >>= 1) v += __shfl_down(v, off);
        if (lane == 0) out[b * 10 + c] = v + bV[c];
    }
}

// ---------------- launch ---------------------------------------------------
// RING ws layout (bytes), total 67,387,392:
//   [0, 33554432)            xs  bf16 [512][64][512]
//   +33554432  h0ring bf16 [128][64][1024]   (16777216)
//   +50331648  h1ring bf16 [128][64][1024]   (16777216)
//   +67108864  h1f    fp32 [64][1024]        (262144)
//   +67371008  flags  [16 banks][256] u32    (16384)
extern "C" void kernel_launch(void* const* d_in, const int* in_sizes, int n_in,
                              void* d_out, int out_size, void* d_ws, size_t ws_size,
                              hipStream_t stream)
{
    const int*   x   = (const int*)d_in[0];
    const float* emb = (const float*)d_in[1];
    const float* W0  = (const float*)d_in[2];
    const float* b0  = (const float*)d_in[3];
    const float* W1  = (const float*)d_in[4];
    const float* b1  = (const float*)d_in[5];
    const float* V   = (const float*)d_in[6];
    const float* bV  = (const float*)d_in[7];
    float* out = (float*)d_out;

    char* ws = (char*)d_ws;
    ush* xs = (ush*)ws;

    if (ws_size >= 67387392ULL) {
        ush*  h0r = (ush*)(ws + 33554432);
        ush*  h1r = (ush*)(ws + 50331648);
        float* h1f = (float*)(ws + OFF_H1F);
        u32*  bar = (u32*)(ws + OFF_BAR);

        hipLaunchKernelGGL(init_kernel, dim3(16), dim3(256), 0, stream, bar, 4096);
        hipLaunchKernelGGL(embed_kernel, dim3(8192), dim3(256), 0, stream, x, emb, xs);
        hipLaunchKernelGGL(lstm_kernel_df, dim3(256), dim3(512), LDS_DF_TOTAL, stream,
                           xs, h0r, h1r, h1f, bar, W0, b0, W1, b1);
        hipLaunchKernelGGL(cls_kernel, dim3(64), dim3(64), 0, stream, h1f, V, bV, out);
    } else {
        char* dyn = ws + 33554432;
        ush*  h0  = (ush*)(dyn);
        ush*  h1  = (ush*)(dyn + 262144);
        float* h1f = (float*)(dyn + 524288);
        u32*  bar = (u32*)(dyn + 786432);

        hipLaunchKernelGGL(init_kernel, dim3(780), dim3(256), 0, stream,
                           (u32*)dyn, 199680);
        hipLaunchKernelGGL(embed_kernel, dim3(8192), dim3(256), 0, stream, x, emb, xs);
        hipLaunchKernelGGL(lstm_kernel_fb, dim3(256), dim3(512), LDS_FB_TOTAL, stream,
                           xs, h0, h1, h1f, bar, W0, b0, W1, b1);
        hipLaunchKernelGGL(cls_kernel, dim3(64), dim3(64), 0, stream, h1f, V, bV, out);
    }
}